// Round 12
// baseline (2076.675 us; speedup 1.0000x reference)
//
#include <hip/hip_runtime.h>
#include <cstdint>

#define NB 64
#define NC 256
#define ND 256
#define NT 4096

#define BT 32                    // t-columns per tile
#define NTILES 16                // tiles per block
#define CHUNK (BT * NTILES)      // 512 t per block
#define NCHUNK (NT / CHUNK)      // 8 chunks -> grid (8, 64) = 512 blocks = 2 per CU

typedef __attribute__((ext_vector_type(8)))  _Float16 half8;
typedef __attribute__((ext_vector_type(16))) float    f32x16;

union FragA { uint32_t u[4]; uint4 q; half8 v; };

__device__ __forceinline__ uint32_t pk_f16(float lo, float hi) {
    return __builtin_bit_cast(uint32_t, __builtin_amdgcn_cvt_pkrtz(lo, hi));
}

// R7/R11 structure (126 µs known-good) + DEPTH-2 REGISTER PREFETCH.
// Diagnosis of the 126 µs plateau: loads for tile T+1 issued at top of tile T
// were consumed at the BOTTOM of the same iteration (~500 cyc later) — less
// than HBM latency (~900 cyc), so every wave stalled at the counted vmcnt
// before the ds_write, every tile. (Store reorder R11 was neutral -> stores
// were never the exposed term.)
// Fix: two stage register sets. At tile T: issue loads T+2 into the free set;
// cvt/ds_write the set holding T+1 (issued a full iteration ~2000+cyc ago —
// latency fully covered). LDS stays double-buffered; depth lives in regs
// (+16 VGPR ~ 80 total, far from the 128 cap / R3 spill cliff).
// Loop unrolled x2 so all stage indexing is static (no scratch).
//
// LDS (per buffer, 16 KiB): fp16 x-tile [t][c], byte(t,c)=t*512+((2c)^((t&15)<<4)).
// MFMA: D[m=d][n=t]; A = W frag (lane&31=d), B = x frag (lane&31=t), k=8g+j.
// C/D: col = lane&31 = t -> coalesced 4B/lane stores.
__global__ __launch_bounds__(512, 4)
void subject_gemm(const float* __restrict__ x,
                  const int*   __restrict__ subjects,
                  const float* __restrict__ w,
                  float*       __restrict__ out)
{
    __shared__ __align__(16) unsigned char lds[2 * 32 * 512];   // 32 KiB total

    const int tid  = threadIdx.x;
    const int lane = tid & 63;
    const int wv   = tid >> 6;      // 0..7 : d-subtile
    const int g    = lane >> 5;     // k-group / c-half
    const int l31  = lane & 31;     // t within tile (and d within subtile for W)
    const int b    = blockIdx.y;
    const int t0   = blockIdx.x * CHUNK;

    const int sub = subjects[b];
    const float* __restrict__ wsub = w + (size_t)sub * NC * ND;
    const float* __restrict__ xb   = x + (size_t)b * NC * NT;
    float*       __restrict__ ob   = out + (size_t)b * ND * NT;

    const int dlane = wv * 32 + l31;

    // ---- one-time: W fragments (fp16) in registers; lane&31 = d, k(c) = 8g+j ----
    half8 wf[16];
#pragma unroll
    for (int ks = 0; ks < 16; ++ks) {
        float f[8];
#pragma unroll
        for (int j = 0; j < 8; ++j)
            f[j] = wsub[(size_t)(ks * 16 + g * 8 + j) * ND + dlane];
        FragA tmp;
#pragma unroll
        for (int p = 0; p < 4; ++p) tmp.u[p] = pk_f16(f[2 * p], f[2 * p + 1]);
        wf[ks] = tmp.v;
    }

    // ---- staging: thread owns c in [c0, c0+16), t = l31 ----
    const int c0 = wv * 32 + g * 16;
    const uint32_t swz      = ((uint32_t)(l31 & 15)) << 4;
    const uint32_t wr_byte0 = (uint32_t)l31 * 512 + (((uint32_t)c0 * 2 +  0) ^ swz);
    const uint32_t wr_byte1 = (uint32_t)l31 * 512 + (((uint32_t)c0 * 2 + 16) ^ swz);
    const uint32_t rd_row   = (uint32_t)l31 * 512;

    const float* xg = xb + (size_t)c0 * NT + t0 + l31;   // + i*NT + tile*BT

    float stageA[16], stageB[16];

#define ISSUE_LOADS(S, tl)                                                  \
    {                                                                       \
        const float* src = xg + (size_t)(tl) * BT;                          \
        _Pragma("unroll")                                                   \
        for (int i = 0; i < 16; ++i) S[i] = src[(size_t)i * NT];            \
        __builtin_amdgcn_sched_barrier(0);                                  \
    }

#define CVT_WRITE(S, bufbyte)                                               \
    {                                                                       \
        uint4 q0, q1;                                                       \
        q0.x = pk_f16(S[0],  S[1]);  q0.y = pk_f16(S[2],  S[3]);            \
        q0.z = pk_f16(S[4],  S[5]);  q0.w = pk_f16(S[6],  S[7]);            \
        q1.x = pk_f16(S[8],  S[9]);  q1.y = pk_f16(S[10], S[11]);           \
        q1.z = pk_f16(S[12], S[13]); q1.w = pk_f16(S[14], S[15]);           \
        *reinterpret_cast<uint4*>(&lds[(bufbyte) + wr_byte0]) = q0;         \
        *reinterpret_cast<uint4*>(&lds[(bufbyte) + wr_byte1]) = q1;         \
    }

#define COMPUTE(acc, bufbyte)                                               \
    {                                                                       \
        acc = (f32x16){};                                                   \
        _Pragma("unroll")                                                   \
        for (int ks = 0; ks < 16; ++ks) {                                   \
            const uint32_t colb = ((uint32_t)(ks * 32 + g * 16)) ^ swz;     \
            FragA a;                                                        \
            a.q = *reinterpret_cast<const uint4*>(                          \
                      &lds[(bufbyte) + rd_row + colb]);                     \
            acc = __builtin_amdgcn_mfma_f32_32x32x16_f16(wf[ks], a.v, acc,  \
                                                         0, 0, 0);          \
        }                                                                   \
    }

#define STORES(acc, tl)                                                     \
    {                                                                       \
        const int tcol = t0 + (tl) * BT;                                    \
        _Pragma("unroll")                                                   \
        for (int rg = 0; rg < 16; ++rg) {                                   \
            const int drow = wv * 32 + (rg & 3) + 8 * (rg >> 2) + 4 * g;    \
            ob[(size_t)drow * NT + tcol + l31] = acc[rg];                   \
        }                                                                   \
    }

    // ---- prologue: tile0 -> A -> LDS buf0 ; tile1 -> B (in flight) ----
    ISSUE_LOADS(stageA, 0);
    ISSUE_LOADS(stageB, 1);
    CVT_WRITE(stageA, 0);        // counted vmcnt: waits A's 16, leaves B in flight
    __syncthreads();

    for (int t2 = 0; t2 < NTILES; t2 += 2) {
        f32x16 acc;

        // ---- even tile T = t2: compute buf0; B(tile t2+1) -> buf1; prefetch A ----
        if (t2 + 2 < NTILES) ISSUE_LOADS(stageA, t2 + 2);
        COMPUTE(acc, 0);
        CVT_WRITE(stageB, 16384);        // t2+1 <= 15 always
        __syncthreads();
        STORES(acc, t2);

        // ---- odd tile T = t2+1: compute buf1; A(tile t2+2) -> buf0; prefetch B ----
        if (t2 + 3 < NTILES) ISSUE_LOADS(stageB, t2 + 3);
        COMPUTE(acc, 16384);
        if (t2 + 2 < NTILES) CVT_WRITE(stageA, 0);
        __syncthreads();
        STORES(acc, t2 + 1);
    }
}

extern "C" void kernel_launch(void* const* d_in, const int* in_sizes, int n_in,
                              void* d_out, int out_size, void* d_ws, size_t ws_size,
                              hipStream_t stream)
{
    const float* x        = (const float*)d_in[0];
    const int*   subjects = (const int*)d_in[1];
    const float* w        = (const float*)d_in[2];
    float*       out      = (float*)d_out;

    dim3 grid(NCHUNK, NB);   // (8, 64) — R7's known-good dispatch layout
    subject_gemm<<<grid, 512, 0, stream>>>(x, subjects, w, out);
}

// Round 13
// 130.002 us; speedup vs baseline: 15.9742x; 15.9742x over previous
//
#include <hip/hip_runtime.h>
#include <cstdint>

#define NB 64
#define NC 256
#define ND 256
#define NT 4096

#define BT 32                    // t-columns per tile
#define NTILES 16                // tiles per block
#define CHUNK (BT * NTILES)      // 512 t per block
#define NCHUNK (NT / CHUNK)      // 8 chunks -> grid (8, 64) = 512 blocks = 2 per CU

typedef __attribute__((ext_vector_type(8)))  _Float16 half8;
typedef __attribute__((ext_vector_type(16))) float    f32x16;

union FragA { uint32_t u[4]; uint4 q; half8 v; };

__device__ __forceinline__ uint32_t pk_f16(float lo, float hi) {
    // v_cvt_pkrtz_f16_f32: D.lo=f16(lo), D.hi=f16(hi) — matches MFMA (k even, k odd) packing
    return __builtin_bit_cast(uint32_t, __builtin_amdgcn_cvt_pkrtz(lo, hi));
}

// EXACT R7 kernel (126 µs known-good) with ONE deletion: the
// __builtin_amdgcn_sched_barrier(0) pinning the prefetch loads at loop-top.
// A/B evidence: R4 (no pin, 1 blk/CU) FETCH=256 MB; R5 (same + pin)
// FETCH=442 MB (+185 MB HBM re-fetch — pinned 16-deep load issue lengthens
// L2 residency windows under store pressure; x-tile cross-wave reuse and
// per-block W re-streams start missing L2). R7/R9 inherit the pin (R9
// FETCH=387 MB). That excess = 21-29 µs of pure BW time ~ the entire
// plateau-to-floor gap. The 2-blocks/CU TLP (R7's win) covers the
// issue-to-use latency that the pin was originally for.
//
// Dead ends so far (keep out): R3/R12 register-depth (spills), R6 custom
// barrier (raced; and no faster than __syncthreads), R8 4 blk/CU (W blowup),
// R9 XCD remap (worse), R10 LDS-free (VMEM-issue-bound), R11 store reorder
// (neutral).
//
// LDS (per buffer, 16 KiB): fp16 x-tile [t=0..31][c=0..255], row = 512 B,
// byte(t,c) = t*512 + ((2c) ^ ((t&15)<<4))  — XOR swizzle, same on write & read.
//
// MFMA: D[m=d][n=t] = sum_c W^T[d][c] * X[c][t]
//   A = W frag (lane&31 = d, k = 8*(lane>>5)+j), B = x frag (lane&31 = t)
//   C/D: col = lane&31 = t -> coalesced 4B/lane stores.
__global__ __launch_bounds__(512, 4)
void subject_gemm(const float* __restrict__ x,
                  const int*   __restrict__ subjects,
                  const float* __restrict__ w,
                  float*       __restrict__ out)
{
    __shared__ __align__(16) unsigned char lds[2 * 32 * 512];   // 32 KiB total

    const int tid  = threadIdx.x;
    const int lane = tid & 63;
    const int wv   = tid >> 6;      // 0..7 : d-subtile
    const int g    = lane >> 5;     // k-group / c-half
    const int l31  = lane & 31;     // t within tile (and d within subtile for W)
    const int b    = blockIdx.y;
    const int t0   = blockIdx.x * CHUNK;

    const int sub = subjects[b];
    const float* __restrict__ wsub = w + (size_t)sub * NC * ND;
    const float* __restrict__ xb   = x + (size_t)b * NC * NT;
    float*       __restrict__ ob   = out + (size_t)b * ND * NT;

    const int dlane = wv * 32 + l31;

    // ---- one-time: W fragments (fp16) in registers; lane&31 = d, k(c) = 8g+j ----
    half8 wf[16];
#pragma unroll
    for (int ks = 0; ks < 16; ++ks) {
        float f[8];
#pragma unroll
        for (int j = 0; j < 8; ++j)
            f[j] = wsub[(size_t)(ks * 16 + g * 8 + j) * ND + dlane];
        FragA tmp;
#pragma unroll
        for (int p = 0; p < 4; ++p) tmp.u[p] = pk_f16(f[2 * p], f[2 * p + 1]);
        wf[ks] = tmp.v;
    }

    // ---- staging: thread owns c in [c0, c0+16), t = l31 ----
    const int c0 = wv * 32 + g * 16;
    const uint32_t swz      = ((uint32_t)(l31 & 15)) << 4;
    const uint32_t wr_byte0 = (uint32_t)l31 * 512 + (((uint32_t)c0 * 2 +  0) ^ swz);
    const uint32_t wr_byte1 = (uint32_t)l31 * 512 + (((uint32_t)c0 * 2 + 16) ^ swz);
    const uint32_t rd_row   = (uint32_t)l31 * 512;

    const float* xg = xb + (size_t)c0 * NT + t0 + l31;   // + i*NT + tile*BT

    float stage[16];

    // prologue: stage tile 0
#pragma unroll
    for (int i = 0; i < 16; ++i) stage[i] = xg[(size_t)i * NT];
    {
        uint4 q0, q1;
        q0.x = pk_f16(stage[0],  stage[1]);  q0.y = pk_f16(stage[2],  stage[3]);
        q0.z = pk_f16(stage[4],  stage[5]);  q0.w = pk_f16(stage[6],  stage[7]);
        q1.x = pk_f16(stage[8],  stage[9]);  q1.y = pk_f16(stage[10], stage[11]);
        q1.z = pk_f16(stage[12], stage[13]); q1.w = pk_f16(stage[14], stage[15]);
        *reinterpret_cast<uint4*>(&lds[wr_byte0]) = q0;
        *reinterpret_cast<uint4*>(&lds[wr_byte1]) = q1;
    }
    __syncthreads();

    for (int tile = 0; tile < NTILES; ++tile) {
        const uint32_t bufoff = (uint32_t)(tile & 1) * 16384;

        // issue next tile's 16 global loads (NOT pinned — compiler placement;
        // the 2-blocks/CU TLP covers the latency, and unpinned issue keeps
        // L2 residency windows short -> less re-fetch)
        if (tile + 1 < NTILES) {
            const float* src = xg + (size_t)(tile + 1) * BT;
#pragma unroll
            for (int i = 0; i < 16; ++i) stage[i] = src[(size_t)i * NT];
        }

        // ---- compute: 32(d) x 32(t) per wave, K=256 in 16 MFMA steps ----
        f32x16 acc = {};
#pragma unroll
        for (int ks = 0; ks < 16; ++ks) {
            const uint32_t colb = ((uint32_t)(ks * 32 + g * 16)) ^ swz;
            FragA a;
            a.q = *reinterpret_cast<const uint4*>(&lds[bufoff + rd_row + colb]);
            acc = __builtin_amdgcn_mfma_f32_32x32x16_f16(wf[ks], a.v, acc, 0, 0, 0);
        }

        // ---- store: col = lane&31 = t ; row d = (reg&3) + 8*(reg>>2) + 4*g ----
        const int tcol = t0 + tile * BT;
#pragma unroll
        for (int rg = 0; rg < 16; ++rg) {
            const int drow = wv * 32 + (rg & 3) + 8 * (rg >> 2) + 4 * g;
            ob[(size_t)drow * NT + tcol + l31] = acc[rg];
        }

        // convert + ds_write staged tile into the other buffer
        if (tile + 1 < NTILES) {
            const uint32_t nb = (uint32_t)((tile + 1) & 1) * 16384;
            uint4 q0, q1;
            q0.x = pk_f16(stage[0],  stage[1]);  q0.y = pk_f16(stage[2],  stage[3]);
            q0.z = pk_f16(stage[4],  stage[5]);  q0.w = pk_f16(stage[6],  stage[7]);
            q1.x = pk_f16(stage[8],  stage[9]);  q1.y = pk_f16(stage[10], stage[11]);
            q1.z = pk_f16(stage[12], stage[13]); q1.w = pk_f16(stage[14], stage[15]);
            *reinterpret_cast<uint4*>(&lds[nb + wr_byte0]) = q0;
            *reinterpret_cast<uint4*>(&lds[nb + wr_byte1]) = q1;
        }
        __syncthreads();
    }
}

extern "C" void kernel_launch(void* const* d_in, const int* in_sizes, int n_in,
                              void* d_out, int out_size, void* d_ws, size_t ws_size,
                              hipStream_t stream)
{
    const float* x        = (const float*)d_in[0];
    const int*   subjects = (const int*)d_in[1];
    const float* w        = (const float*)d_in[2];
    float*       out      = (float*)d_out;

    dim3 grid(NCHUNK, NB);   // (8, 64) — R7's known-good dispatch layout
    subject_gemm<<<grid, 512, 0, stream>>>(x, subjects, w, out);
}